// Round 18
// baseline (168.404 us; speedup 1.0000x reference)
//
#include <hip/hip_runtime.h>
#include <stdint.h>

// ---------------------------------------------------------------------------
// BitAttention round 17:
//   - flash_attn v13: DUAL-Q-CONTEXT tiles. Each block processes its paired
//     q-tiles (lbx, 15-lbx) in ONE K/V sweep with two independent softmax
//     states: shared kf/vf LDS reads, two independent MFMA<->VALU chains per
//     tile (intra-wave overlap), staged tiles 34 -> 32-2*lbx (avg -26%).
//     Barrier scheme = r14's known-good (__syncthreads, stage-after-QK^T);
//     r16's counted-vmcnt attn variant REVERTED (regressed).
//   - gemm_dp BN=192/128 counted-vmcnt pipeline, prep_all: unchanged.
// ws layout (bytes):
//   [0,5120)    double partials[640]
//   [6144,6304) float tabs[4]: sq*log2e, sk, sv, so
//   [8192,...)  xb(16M) wqkvs(12M) wos(8M) qkvb(24M) ao(16M) vt(4M)
// ---------------------------------------------------------------------------

#define D_MODEL 2048
#define S_LEN   2048
#define BATCH   2
#define NKV     8
#define HD      64
#define MROWS   (BATCH * S_LEN)   // 4096
#define NQKV    3072
#define LDQKV   3072

typedef unsigned short u16;
typedef __bf16 bf16x8 __attribute__((ext_vector_type(8)));
typedef float  f32x4  __attribute__((ext_vector_type(4)));
typedef float  f32x16 __attribute__((ext_vector_type(16)));
typedef unsigned u32x4 __attribute__((ext_vector_type(4)));

__device__ __forceinline__ u16 f2bf(float f) {
  union { float f; unsigned u; } v; v.f = f;
  unsigned r = v.u + 0x7FFFu + ((v.u >> 16) & 1u);   // RNE
  return (u16)(r >> 16);
}

__device__ __forceinline__ float exp2_fast(float x) {
  float r; asm("v_exp_f32 %0, %1" : "=v"(r) : "v"(x)); return r;
}

__device__ __forceinline__ unsigned cvt_pk_bf16(float a, float b) {
  unsigned r;
  asm("v_cvt_pk_bf16_f32 %0, %1, %2" : "=v"(r) : "v"(a), "v"(b));
  return r;
}

__device__ __forceinline__ void lds_load16(u16* lds, const u16* g) {
  __builtin_amdgcn_global_load_lds(
      (const __attribute__((address_space(1))) void*)g,
      (__attribute__((address_space(3))) void*)lds, 16, 0, 0);
}

#define SM_LOG2E 0.180336880f   // (1/sqrt(64)) * log2(e); folded into Q cols
#define THR_LOG2 11.5415603f    // 8 * log2(e)

// ---------------- fused prep: weight sign+|w| partials, x->bf16 ----------------
__global__ void prep_all(const float* __restrict__ wq, const float* __restrict__ wk,
                         const float* __restrict__ wv, const float* __restrict__ wo,
                         const float* __restrict__ x,
                         u16* __restrict__ wqkvs, u16* __restrict__ wos,
                         u16* __restrict__ xb, double* __restrict__ partials) {
  const int bid = blockIdx.x;
  const float* src; u16* dst; int n4, rb, nb; bool sgn = true;
  if (bid < 256)      { src = wq; dst = wqkvs;                  n4 = 1048576; rb = bid;       nb = 256; }
  else if (bid < 320) { src = wk; dst = wqkvs + 2048 * D_MODEL; n4 = 262144;  rb = bid - 256; nb = 64;  }
  else if (bid < 384) { src = wv; dst = wqkvs + 2560 * D_MODEL; n4 = 262144;  rb = bid - 320; nb = 64;  }
  else if (bid < 640) { src = wo; dst = wos;                    n4 = 1048576; rb = bid - 384; nb = 256; }
  else                { src = x;  dst = xb;                     n4 = 2097152; rb = bid - 640; nb = 512; sgn = false; }

  if (sgn) {
    double s = 0.0;
    for (int i = rb * 256 + threadIdx.x; i < n4; i += nb * 256) {
      float4 v = reinterpret_cast<const float4*>(src)[i];
      ushort4 o;
      o.x = v.x > 0.f ? 0x3F80 : (v.x < 0.f ? 0xBF80 : 0);
      o.y = v.y > 0.f ? 0x3F80 : (v.y < 0.f ? 0xBF80 : 0);
      o.z = v.z > 0.f ? 0x3F80 : (v.z < 0.f ? 0xBF80 : 0);
      o.w = v.w > 0.f ? 0x3F80 : (v.w < 0.f ? 0xBF80 : 0);
      reinterpret_cast<ushort4*>(dst)[i] = o;
      s += (double)fabsf(v.x) + (double)fabsf(v.y) +
           (double)fabsf(v.z) + (double)fabsf(v.w);
    }
    __shared__ double sm[256];
    sm[threadIdx.x] = s;
    __syncthreads();
    for (int off = 128; off > 0; off >>= 1) {
      if (threadIdx.x < off) sm[threadIdx.x] += sm[threadIdx.x + off];
      __syncthreads();
    }
    if (threadIdx.x == 0) partials[bid] = sm[0];
  } else {
    for (int i = rb * 256 + threadIdx.x; i < n4; i += nb * 256) {
      float4 v = reinterpret_cast<const float4*>(src)[i];
      ushort4 o;
      o.x = f2bf(v.x); o.y = f2bf(v.y); o.z = f2bf(v.z); o.w = f2bf(v.w);
      reinterpret_cast<ushort4*>(dst)[i] = o;
    }
  }
}

// 4 waves, one per weight; butterfly reduce (deterministic fixed tree).
__global__ void finalize_scales(const double* __restrict__ partials,
                                float* __restrict__ tabs) {
  __shared__ float sc_sh[4];
  const int w = threadIdx.x >> 6;
  const int lane = threadIdx.x & 63;
  const int beg[4] = {0, 256, 320, 384};
  const int cnt[4] = {256, 64, 64, 256};
  const double counts[4] = {4194304.0, 1048576.0, 1048576.0, 4194304.0};
  double s = 0.0;
  for (int i = lane; i < cnt[w]; i += 64) s += partials[beg[w] + i];
  for (int off = 1; off < 64; off <<= 1) s += __shfl_xor(s, off);
  if (lane == 0) sc_sh[w] = fmaxf((float)(s / counts[w]), 1e-5f);
  __syncthreads();
  if (threadIdx.x == 0) {
    tabs[0] = sc_sh[0] * SM_LOG2E;
    tabs[1] = sc_sh[1];
    tabs[2] = sc_sh[2];
    tabs[3] = sc_sh[3];
  }
}

// ---------------- deep-pipeline GEMM (templated BN) ----------------
template <int BN, int OUT_BF16, int QKVMODE>
__global__ __launch_bounds__(512, 4) void gemm_dp(
    const u16* __restrict__ A, const u16* __restrict__ Bt, void* __restrict__ Cv,
    const float* __restrict__ tabs4, u16* __restrict__ vt, int M, int N, int K) {
  constexpr int WN = BN / 4;
  constexpr int NFR = WN / 16;
  constexpr int BITER = BN / 64;
  __shared__ u16 lA[2][128 * 64];
  __shared__ u16 lB[2][BN * 64];
  const int tid = threadIdx.x;
  const int lane = tid & 63, wave = tid >> 6;
  const int lo = lane & 15, hi = lane >> 4;
  const int m0 = blockIdx.y * 128, n0 = blockIdx.x * BN;
  const int wr = (wave >> 2) * 64;
  const int wc = (wave & 3) * WN;
  const int swl = (lo & 7) << 3;

  f32x4 acc[4][NFR] = {};
  const int nt = K >> 6;

  auto STAGE = [&](int bf, int kt) {
    const int k0s = kt * 64;
#pragma unroll
    for (int it = 0; it < 2; ++it) {
      const int c = it * 512 + tid;
      const int row = c >> 3;
      const int ch = (c & 7) ^ (row & 7);
      lds_load16(&lA[bf][(it * 512 + wave * 64) * 8],
                 &A[(size_t)(m0 + row) * K + k0s + ch * 8]);
    }
#pragma unroll
    for (int it = 0; it < BITER; ++it) {
      const int c = it * 512 + tid;
      const int row = c >> 3;
      const int ch = (c & 7) ^ (row & 7);
      lds_load16(&lB[bf][(it * 512 + wave * 64) * 8],
                 &Bt[(size_t)(n0 + row) * K + k0s + ch * 8]);
    }
  };

  STAGE(0, 0);
  STAGE(1, 1);

#pragma unroll 1
  for (int kt = 0; kt < nt; ++kt) {
    const int cur = kt & 1;
    if (kt + 1 < nt) {
      if constexpr (BITER == 3)
        asm volatile("s_waitcnt vmcnt(5)\n\ts_barrier" ::: "memory");
      else
        asm volatile("s_waitcnt vmcnt(4)\n\ts_barrier" ::: "memory");
    } else {
      asm volatile("s_waitcnt vmcnt(0)\n\ts_barrier" ::: "memory");
    }
    __builtin_amdgcn_sched_barrier(0);

    const u16* la = lA[cur];
    const u16* lb = lB[cur];
#pragma unroll
    for (int kk = 0; kk < 2; ++kk) {
      bf16x8 af[4], bfr[NFR];
#pragma unroll
      for (int i = 0; i < 4; ++i)
        af[i] = *reinterpret_cast<const bf16x8*>(
            &la[(wr + i * 16 + lo) * 64 + ((kk * 32 + hi * 8) ^ swl)]);
#pragma unroll
      for (int i = 0; i < NFR; ++i)
        bfr[i] = *reinterpret_cast<const bf16x8*>(
            &lb[(wc + i * 16 + lo) * 64 + ((kk * 32 + hi * 8) ^ swl)]);
      __builtin_amdgcn_s_setprio(1);
#pragma unroll
      for (int mi = 0; mi < 4; ++mi)
#pragma unroll
        for (int ni = 0; ni < NFR; ++ni)
          acc[mi][ni] = __builtin_amdgcn_mfma_f32_16x16x32_bf16(
              af[mi], bfr[ni], acc[mi][ni], 0, 0, 0);
      __builtin_amdgcn_s_setprio(0);
    }
    __builtin_amdgcn_sched_barrier(0);
    asm volatile("s_barrier" ::: "memory");
    if (kt + 2 < nt) STAGE(cur, kt + 2);
  }

  const float s0 = tabs4[0];
#pragma unroll
  for (int mi = 0; mi < 4; ++mi) {
#pragma unroll
    for (int ni = 0; ni < NFR; ++ni) {
      const int col0 = n0 + wc + ni * 16;   // frag-uniform (16-aligned)
      float scale = s0;
      if (QKVMODE) scale = col0 < 2048 ? s0 : (col0 < 2560 ? tabs4[1] : tabs4[2]);
      if (QKVMODE && col0 >= 2560) {
        const int vcol = col0 - 2560 + lo;
        const int row = m0 + wr + mi * 16 + hi * 4;
        unsigned w01 = cvt_pk_bf16(acc[mi][ni][0] * scale, acc[mi][ni][1] * scale);
        unsigned w23 = cvt_pk_bf16(acc[mi][ni][2] * scale, acc[mi][ni][3] * scale);
        uint2 pk; pk.x = w01; pk.y = w23;
        *reinterpret_cast<uint2*>(vt + (size_t)vcol * MROWS + row) = pk;
      } else {
#pragma unroll
        for (int r = 0; r < 4; ++r) {
          const int row = m0 + wr + mi * 16 + hi * 4 + r;
          const int col = col0 + lo;
          const float v = acc[mi][ni][r] * scale;
          if (OUT_BF16)
            reinterpret_cast<u16*>(Cv)[(size_t)row * N + col] = f2bf(v);
          else
            reinterpret_cast<float*>(Cv)[(size_t)row * N + col] = v;
        }
      }
    }
  }
}

// ---------------- flash attention v13 (dual-Q-context, 32x32, permlane) --------
__device__ __forceinline__ void stage_tile(u16* dst, const u16* base, int ld,
                                           int tid, int wave) {
#pragma unroll
  for (int it = 0; it < 2; ++it) {
    const int c = it * 256 + tid;
    const int row = c >> 3;
    const int ch = (c & 7) ^ (row & 7);   // pre-swizzled source (rule #21)
    lds_load16(dst + (it * 256 + wave * 64) * 8, base + (size_t)row * ld + ch * 8);
  }
}

// Online-softmax for one context: mask (runtime, last 2 tiles), tree max,
// defer-max rescale, exp2 + packed P (pk[2][8]).
#define SM_CTX(SACC, MRUN, LRUN, OACC, QG, NTX, PK)                            \
  {                                                                            \
    if (ti >= (NTX) - 2) {                                                     \
      _Pragma("unroll")                                                        \
      for (int nf = 0; nf < 2; ++nf) {                                         \
        _Pragma("unroll")                                                      \
        for (int rg = 0; rg < 16; ++rg) {                                      \
          const int tg = t0 + nf * 32 + (rg >> 2) * 8 + hi5 * 4 + (rg & 3);    \
          if (tg > (QG)) SACC[nf][rg] = -1e30f;                                \
        }                                                                      \
      }                                                                        \
    }                                                                          \
    float mt = -1e30f;                                                         \
    _Pragma("unroll")                                                          \
    for (int nf = 0; nf < 2; ++nf) {                                           \
      _Pragma("unroll")                                                        \
      for (int rg = 0; rg < 16; ++rg) mt = fmaxf(mt, SACC[nf][rg]);            \
    }                                                                          \
    mt = fmaxf(mt, __shfl_xor(mt, 32));                                        \
    if (!__all((int)(mt <= MRUN + THR_LOG2))) {                                \
      const float mn = fmaxf(MRUN, mt);                                        \
      const float alpha = exp2_fast(MRUN - mn);                                \
      MRUN = mn;                                                               \
      LRUN *= alpha;                                                           \
      _Pragma("unroll")                                                        \
      for (int nf = 0; nf < 2; ++nf) {                                         \
        _Pragma("unroll")                                                      \
        for (int rg = 0; rg < 16; ++rg) OACC[nf][rg] *= alpha;                 \
      }                                                                        \
    }                                                                          \
    _Pragma("unroll")                                                          \
    for (int nf = 0; nf < 2; ++nf) {                                           \
      _Pragma("unroll")                                                        \
      for (int c = 0; c < 4; ++c) {                                            \
        const float e0 = exp2_fast(SACC[nf][4 * c + 0] - MRUN);                \
        const float e1 = exp2_fast(SACC[nf][4 * c + 1] - MRUN);                \
        const float e2 = exp2_fast(SACC[nf][4 * c + 2] - MRUN);                \
        const float e3 = exp2_fast(SACC[nf][4 * c + 3] - MRUN);                \
        LRUN += (e0 + e1) + (e2 + e3);                                         \
        PK[nf][2 * c + 0] = cvt_pk_bf16(e0, e1);                               \
        PK[nf][2 * c + 1] = cvt_pk_bf16(e2, e3);                               \
      }                                                                        \
    }                                                                          \
  }

// Build PV A-fragment for window W from packed P (permlane32_swap pair).
#define PFR(PK, W, OUT)                                                        \
  bf16x8 OUT;                                                                  \
  {                                                                            \
    const int nf_ = (W) >> 1, c4_ = ((W) & 1) * 4;                             \
    unsigned a0 = PK[nf_][c4_ + 0], a1 = PK[nf_][c4_ + 1];                     \
    unsigned b0 = PK[nf_][c4_ + 2], b1 = PK[nf_][c4_ + 3];                     \
    asm volatile("v_permlane32_swap_b32 %0, %1" : "+v"(a0), "+v"(b0));         \
    asm volatile("v_permlane32_swap_b32 %0, %1" : "+v"(a1), "+v"(b1));         \
    u32x4 pw; pw.x = a0; pw.y = a1; pw.z = b0; pw.w = b1;                      \
    OUT = *reinterpret_cast<const bf16x8*>(&pw);                               \
  }

#define EPILOGUE(OACC, LRUN, Q0W)                                              \
  {                                                                            \
    const float ls = LRUN + __shfl_xor(LRUN, 32);                              \
    const float inv = 1.f / ls;                                                \
    _Pragma("unroll")                                                          \
    for (int nfo = 0; nfo < 2; ++nfo) {                                        \
      _Pragma("unroll")                                                        \
      for (int c = 0; c < 4; ++c) {                                            \
        const unsigned u0 = cvt_pk_bf16(OACC[nfo][4 * c + 0] * inv,            \
                                        OACC[nfo][4 * c + 1] * inv);           \
        const unsigned u1 = cvt_pk_bf16(OACC[nfo][4 * c + 2] * inv,            \
                                        OACC[nfo][4 * c + 3] * inv);           \
        const int d = nfo * 32 + c * 8 + hi5 * 4;                              \
        uint2 st; st.x = u0; st.y = u1;                                        \
        *reinterpret_cast<uint2*>(                                             \
            &Og[(size_t)(brow + (Q0W) + q31) * D_MODEL + h * HD + d]) = st;    \
      }                                                                        \
    }                                                                          \
  }

__global__ __launch_bounds__(256, 2) void flash_attn(
    const u16* __restrict__ QKV, const u16* __restrict__ VT,
    u16* __restrict__ Og) {
  __shared__ u16 lK[2][64 * 64];    // [t][d], XOR-swizzled chunks
  __shared__ u16 lV[2][64 * 64];    // [d][t], XOR-swizzled chunks

  const int tid = threadIdx.x;
  const int lane = tid & 63, wave = tid >> 6;
  const int q31 = lane & 31, hi5 = lane >> 5;
  // XCD group pinning (round-8): each (b,kv) group's 32 blocks on one XCD.
  const int lin = (int)blockIdx.y * 8 + (int)blockIdx.x;   // 0..511
  const int xcd = lin & 7, slot = lin >> 3;
  const int G = xcd * 2 + (slot >> 5);    // 0..15 = (b, kv)
  const int wb = slot & 31;               // 0..31 = (g_h, lbx)
  const int b = G >> 3, kv = G & 7;
  const int h = kv * 4 + (wb >> 3);
  const int lbx = wb & 7;
  const int brow = b * S_LEN;
  const u16* Q  = QKV + h * HD;
  const u16* Kb = QKV + 2048 + kv * HD;                   // row stride LDQKV
  const u16* Vb = VT + (size_t)(kv * HD) * MROWS + brow;  // row d, stride MROWS
  const int swl = (lane & 7) << 3;

  // two q-tile contexts sharing one K/V sweep
  const int ntA = 2 * lbx + 2;            // short context
  const int ntB = 32 - 2 * lbx;           // long context (ntA <= ntB)
  const int q0wA = lbx * 128 + wave * 32;
  const int q0wB = (15 - lbx) * 128 + wave * 32;
  const int qgA = q0wA + q31, qgB = q0wB + q31;

  bf16x8 qfA[4], qfB[4];
  {
    const size_t qrA = (size_t)(brow + q0wA + q31) * LDQKV;
    const size_t qrB = (size_t)(brow + q0wB + q31) * LDQKV;
#pragma unroll
    for (int w = 0; w < 4; ++w) {
      qfA[w] = *reinterpret_cast<const bf16x8*>(&Q[qrA + w * 16 + hi5 * 8]);
      qfB[w] = *reinterpret_cast<const bf16x8*>(&Q[qrB + w * 16 + hi5 * 8]);
    }
  }

  f32x16 oA[2] = {}, oB[2] = {};
  float mA = -1e30f, lA_ = 0.f, mB = -1e30f, lB_ = 0.f;
  int cur = 0;

  // prologue: stage tile 0
  stage_tile(lK[0], Kb + (size_t)brow * LDQKV, LDQKV, tid, wave);
  stage_tile(lV[0], Vb, MROWS, tid, wave);
  __syncthreads();

#pragma unroll 1
  for (int ti = 0; ti < ntB; ++ti) {
    const int t0 = ti * 64;
    u16* lKc = (u16*)lK[cur];
    u16* lVc = (u16*)lV[cur];
    const bool actA = ti < ntA;

    // ---- QK^T for both contexts (shared kf reads) ----
    f32x16 sA[2] = {}, sB[2] = {};
    __builtin_amdgcn_s_setprio(1);
    if (actA) {
#pragma unroll
      for (int w = 0; w < 4; ++w) {
#pragma unroll
        for (int nf = 0; nf < 2; ++nf) {
          bf16x8 kf = *reinterpret_cast<const bf16x8*>(
              &lKc[(nf * 32 + q31) * 64 + ((w * 16 + hi5 * 8) ^ swl)]);
          sA[nf] = __builtin_amdgcn_mfma_f32_32x32x16_bf16(kf, qfA[w], sA[nf], 0, 0, 0);
          sB[nf] = __builtin_amdgcn_mfma_f32_32x32x16_bf16(kf, qfB[w], sB[nf], 0, 0, 0);
        }
      }
    } else {
#pragma unroll
      for (int w = 0; w < 4; ++w) {
#pragma unroll
        for (int nf = 0; nf < 2; ++nf) {
          bf16x8 kf = *reinterpret_cast<const bf16x8*>(
              &lKc[(nf * 32 + q31) * 64 + ((w * 16 + hi5 * 8) ^ swl)]);
          sB[nf] = __builtin_amdgcn_mfma_f32_32x32x16_bf16(kf, qfB[w], sB[nf], 0, 0, 0);
        }
      }
    }
    __builtin_amdgcn_s_setprio(0);

    // ---- prefetch next tile ----
    if (ti + 1 < ntB) {
      stage_tile(lK[cur ^ 1], Kb + (size_t)(brow + t0 + 64) * LDQKV, LDQKV, tid, wave);
      stage_tile(lV[cur ^ 1], Vb + t0 + 64, MROWS, tid, wave);
    }

    // ---- softmax per context (independent chains -> pipe overlap) ----
    unsigned pkA[2][8], pkB[2][8];
    if (actA) SM_CTX(sA, mA, lA_, oA, qgA, ntA, pkA)
    SM_CTX(sB, mB, lB_, oB, qgB, ntB, pkB)

    // ---- PV for both contexts (shared vf reads) ----
    __builtin_amdgcn_s_setprio(1);
    if (actA) {
#pragma unroll
      for (int w = 0; w < 4; ++w) {
        PFR(pkA, w, pfA)
        PFR(pkB, w, pfB)
#pragma unroll
        for (int nfo = 0; nfo < 2; ++nfo) {
          bf16x8 vf = *reinterpret_cast<const bf16x8*>(
              &lVc[(nfo * 32 + q31) * 64 + ((w * 16 + hi5 * 8) ^ swl)]);
          oA[nfo] = __builtin_amdgcn_mfma_f32_32x32x16_bf16(vf, pfA, oA[nfo], 0, 0, 0);
          oB[nfo] = __builtin_amdgcn_mfma_f32_32x32x16_bf16(vf, pfB, oB[nfo], 0, 0, 0);
        }
      }
    } else {
#pragma unroll
      for (int w = 0; w < 4; ++w) {
        PFR(pkB, w, pfB)
#pragma unroll
        for (int nfo = 0; nfo < 2; ++nfo) {
          bf16x8 vf = *reinterpret_cast<const bf16x8*>(
              &lVc[(nfo * 32 + q31) * 64 + ((w * 16 + hi5 * 8) ^ swl)]);
          oB[nfo] = __builtin_amdgcn_mfma_f32_32x32x16_bf16(vf, pfB, oB[nfo], 0, 0, 0);
        }
      }
    }
    __builtin_amdgcn_s_setprio(0);
    __syncthreads();   // all reads of cur done before restage target flips
    cur ^= 1;
  }

  // ---- epilogues ----
  EPILOGUE(oA, lA_, q0wA)
  EPILOGUE(oB, lB_, q0wB)
}

// ---------------- launcher ----------------
extern "C" void kernel_launch(void* const* d_in, const int* in_sizes, int n_in,
                              void* d_out, int out_size, void* d_ws, size_t ws_size,
                              hipStream_t stream) {
  (void)in_sizes; (void)n_in; (void)out_size; (void)ws_size;
  const float* x  = (const float*)d_in[0];
  const float* wq = (const float*)d_in[1];
  const float* wk = (const float*)d_in[2];
  const float* wv = (const float*)d_in[3];
  const float* wo = (const float*)d_in[4];
  float* out = (float*)d_out;
  char* ws = (char*)d_ws;

  double* partials = (double*)ws;            // 640 * 8 B
  float* tabs = (float*)(ws + 6144);         // 4 floats
  size_t off = 8192;
  u16* xb    = (u16*)(ws + off); off += (size_t)MROWS * D_MODEL * 2;
  u16* wqkvs = (u16*)(ws + off); off += (size_t)NQKV * D_MODEL * 2;
  u16* wos   = (u16*)(ws + off); off += (size_t)D_MODEL * D_MODEL * 2;
  u16* qkvb  = (u16*)(ws + off); off += (size_t)MROWS * NQKV * 2;
  u16* ao    = (u16*)(ws + off); off += (size_t)MROWS * D_MODEL * 2;
  u16* vt    = (u16*)(ws + off); off += (size_t)512 * MROWS * 2;

  // 1. fused prep: weight signs + |w| partials + x->bf16
  prep_all<<<1152, 256, 0, stream>>>(wq, wk, wv, wo, x, wqkvs, wos, xb, partials);
  finalize_scales<<<1, 256, 0, stream>>>(partials, tabs);

  // 2. fused QKV projection (BN=192 -> 512 blocks, exactly 2/CU)
  gemm_dp<192, 1, 1><<<dim3(NQKV / 192, MROWS / 128), 512, 0, stream>>>(
      xb, wqkvs, qkvb, tabs, vt, MROWS, NQKV, D_MODEL);

  // 3. GQA causal flash attention (dual-Q-context single K/V sweep)
  flash_attn<<<dim3(8, 64), 256, 0, stream>>>(qkvb, vt, ao);

  // 4. output projection (BN=128 -> 512 blocks, f32 out)
  gemm_dp<128, 0, 0><<<dim3(D_MODEL / 128, MROWS / 128), 512, 0, stream>>>(
      ao, wos, out, tabs + 3, nullptr, MROWS, D_MODEL, D_MODEL);
}

// Round 19
// 158.612 us; speedup vs baseline: 1.0617x; 1.0617x over previous
//
#include <hip/hip_runtime.h>
#include <stdint.h>

// ---------------------------------------------------------------------------
// BitAttention round 18:
//   - REVERT r17 dual-context (regressed; VGPR 124).
//   - flash_attn v14 = r14 paired structure with KVBLK=128 STAGING
//     (compute = two sequential 64-t sub-tiles per staged big tile):
//     barriers/block 35 -> 18, per-barrier compute x2, registers unchanged.
//   - gemm_dp BN=192/128 counted-vmcnt pipeline, prep_all: unchanged.
// ws layout (bytes):
//   [0,5120)    double partials[640]
//   [6144,6304) float tabs[4]: sq*log2e, sk, sv, so
//   [8192,...)  xb(16M) wqkvs(12M) wos(8M) qkvb(24M) ao(16M) vt(4M)
// ---------------------------------------------------------------------------

#define D_MODEL 2048
#define S_LEN   2048
#define BATCH   2
#define NKV     8
#define HD      64
#define MROWS   (BATCH * S_LEN)   // 4096
#define NQKV    3072
#define LDQKV   3072

typedef unsigned short u16;
typedef __bf16 bf16x8 __attribute__((ext_vector_type(8)));
typedef float  f32x4  __attribute__((ext_vector_type(4)));
typedef float  f32x16 __attribute__((ext_vector_type(16)));
typedef unsigned u32x4 __attribute__((ext_vector_type(4)));

__device__ __forceinline__ u16 f2bf(float f) {
  union { float f; unsigned u; } v; v.f = f;
  unsigned r = v.u + 0x7FFFu + ((v.u >> 16) & 1u);   // RNE
  return (u16)(r >> 16);
}

__device__ __forceinline__ float exp2_fast(float x) {
  float r; asm("v_exp_f32 %0, %1" : "=v"(r) : "v"(x)); return r;
}

__device__ __forceinline__ unsigned cvt_pk_bf16(float a, float b) {
  unsigned r;
  asm("v_cvt_pk_bf16_f32 %0, %1, %2" : "=v"(r) : "v"(a), "v"(b));
  return r;
}

__device__ __forceinline__ void lds_load16(u16* lds, const u16* g) {
  __builtin_amdgcn_global_load_lds(
      (const __attribute__((address_space(1))) void*)g,
      (__attribute__((address_space(3))) void*)lds, 16, 0, 0);
}

#define SM_LOG2E 0.180336880f   // (1/sqrt(64)) * log2(e); folded into Q cols
#define THR_LOG2 11.5415603f    // 8 * log2(e)

// ---------------- fused prep: weight sign+|w| partials, x->bf16 ----------------
__global__ void prep_all(const float* __restrict__ wq, const float* __restrict__ wk,
                         const float* __restrict__ wv, const float* __restrict__ wo,
                         const float* __restrict__ x,
                         u16* __restrict__ wqkvs, u16* __restrict__ wos,
                         u16* __restrict__ xb, double* __restrict__ partials) {
  const int bid = blockIdx.x;
  const float* src; u16* dst; int n4, rb, nb; bool sgn = true;
  if (bid < 256)      { src = wq; dst = wqkvs;                  n4 = 1048576; rb = bid;       nb = 256; }
  else if (bid < 320) { src = wk; dst = wqkvs + 2048 * D_MODEL; n4 = 262144;  rb = bid - 256; nb = 64;  }
  else if (bid < 384) { src = wv; dst = wqkvs + 2560 * D_MODEL; n4 = 262144;  rb = bid - 320; nb = 64;  }
  else if (bid < 640) { src = wo; dst = wos;                    n4 = 1048576; rb = bid - 384; nb = 256; }
  else                { src = x;  dst = xb;                     n4 = 2097152; rb = bid - 640; nb = 512; sgn = false; }

  if (sgn) {
    double s = 0.0;
    for (int i = rb * 256 + threadIdx.x; i < n4; i += nb * 256) {
      float4 v = reinterpret_cast<const float4*>(src)[i];
      ushort4 o;
      o.x = v.x > 0.f ? 0x3F80 : (v.x < 0.f ? 0xBF80 : 0);
      o.y = v.y > 0.f ? 0x3F80 : (v.y < 0.f ? 0xBF80 : 0);
      o.z = v.z > 0.f ? 0x3F80 : (v.z < 0.f ? 0xBF80 : 0);
      o.w = v.w > 0.f ? 0x3F80 : (v.w < 0.f ? 0xBF80 : 0);
      reinterpret_cast<ushort4*>(dst)[i] = o;
      s += (double)fabsf(v.x) + (double)fabsf(v.y) +
           (double)fabsf(v.z) + (double)fabsf(v.w);
    }
    __shared__ double sm[256];
    sm[threadIdx.x] = s;
    __syncthreads();
    for (int off = 128; off > 0; off >>= 1) {
      if (threadIdx.x < off) sm[threadIdx.x] += sm[threadIdx.x + off];
      __syncthreads();
    }
    if (threadIdx.x == 0) partials[bid] = sm[0];
  } else {
    for (int i = rb * 256 + threadIdx.x; i < n4; i += nb * 256) {
      float4 v = reinterpret_cast<const float4*>(src)[i];
      ushort4 o;
      o.x = f2bf(v.x); o.y = f2bf(v.y); o.z = f2bf(v.z); o.w = f2bf(v.w);
      reinterpret_cast<ushort4*>(dst)[i] = o;
    }
  }
}

// 4 waves, one per weight; butterfly reduce (deterministic fixed tree).
__global__ void finalize_scales(const double* __restrict__ partials,
                                float* __restrict__ tabs) {
  __shared__ float sc_sh[4];
  const int w = threadIdx.x >> 6;
  const int lane = threadIdx.x & 63;
  const int beg[4] = {0, 256, 320, 384};
  const int cnt[4] = {256, 64, 64, 256};
  const double counts[4] = {4194304.0, 1048576.0, 1048576.0, 4194304.0};
  double s = 0.0;
  for (int i = lane; i < cnt[w]; i += 64) s += partials[beg[w] + i];
  for (int off = 1; off < 64; off <<= 1) s += __shfl_xor(s, off);
  if (lane == 0) sc_sh[w] = fmaxf((float)(s / counts[w]), 1e-5f);
  __syncthreads();
  if (threadIdx.x == 0) {
    tabs[0] = sc_sh[0] * SM_LOG2E;
    tabs[1] = sc_sh[1];
    tabs[2] = sc_sh[2];
    tabs[3] = sc_sh[3];
  }
}

// ---------------- deep-pipeline GEMM (templated BN) ----------------
template <int BN, int OUT_BF16, int QKVMODE>
__global__ __launch_bounds__(512, 4) void gemm_dp(
    const u16* __restrict__ A, const u16* __restrict__ Bt, void* __restrict__ Cv,
    const float* __restrict__ tabs4, u16* __restrict__ vt, int M, int N, int K) {
  constexpr int WN = BN / 4;
  constexpr int NFR = WN / 16;
  constexpr int BITER = BN / 64;
  __shared__ u16 lA[2][128 * 64];
  __shared__ u16 lB[2][BN * 64];
  const int tid = threadIdx.x;
  const int lane = tid & 63, wave = tid >> 6;
  const int lo = lane & 15, hi = lane >> 4;
  const int m0 = blockIdx.y * 128, n0 = blockIdx.x * BN;
  const int wr = (wave >> 2) * 64;
  const int wc = (wave & 3) * WN;
  const int swl = (lo & 7) << 3;

  f32x4 acc[4][NFR] = {};
  const int nt = K >> 6;

  auto STAGE = [&](int bf, int kt) {
    const int k0s = kt * 64;
#pragma unroll
    for (int it = 0; it < 2; ++it) {
      const int c = it * 512 + tid;
      const int row = c >> 3;
      const int ch = (c & 7) ^ (row & 7);
      lds_load16(&lA[bf][(it * 512 + wave * 64) * 8],
                 &A[(size_t)(m0 + row) * K + k0s + ch * 8]);
    }
#pragma unroll
    for (int it = 0; it < BITER; ++it) {
      const int c = it * 512 + tid;
      const int row = c >> 3;
      const int ch = (c & 7) ^ (row & 7);
      lds_load16(&lB[bf][(it * 512 + wave * 64) * 8],
                 &Bt[(size_t)(n0 + row) * K + k0s + ch * 8]);
    }
  };

  STAGE(0, 0);
  STAGE(1, 1);

#pragma unroll 1
  for (int kt = 0; kt < nt; ++kt) {
    const int cur = kt & 1;
    if (kt + 1 < nt) {
      if constexpr (BITER == 3)
        asm volatile("s_waitcnt vmcnt(5)\n\ts_barrier" ::: "memory");
      else
        asm volatile("s_waitcnt vmcnt(4)\n\ts_barrier" ::: "memory");
    } else {
      asm volatile("s_waitcnt vmcnt(0)\n\ts_barrier" ::: "memory");
    }
    __builtin_amdgcn_sched_barrier(0);

    const u16* la = lA[cur];
    const u16* lb = lB[cur];
#pragma unroll
    for (int kk = 0; kk < 2; ++kk) {
      bf16x8 af[4], bfr[NFR];
#pragma unroll
      for (int i = 0; i < 4; ++i)
        af[i] = *reinterpret_cast<const bf16x8*>(
            &la[(wr + i * 16 + lo) * 64 + ((kk * 32 + hi * 8) ^ swl)]);
#pragma unroll
      for (int i = 0; i < NFR; ++i)
        bfr[i] = *reinterpret_cast<const bf16x8*>(
            &lb[(wc + i * 16 + lo) * 64 + ((kk * 32 + hi * 8) ^ swl)]);
      __builtin_amdgcn_s_setprio(1);
#pragma unroll
      for (int mi = 0; mi < 4; ++mi)
#pragma unroll
        for (int ni = 0; ni < NFR; ++ni)
          acc[mi][ni] = __builtin_amdgcn_mfma_f32_16x16x32_bf16(
              af[mi], bfr[ni], acc[mi][ni], 0, 0, 0);
      __builtin_amdgcn_s_setprio(0);
    }
    __builtin_amdgcn_sched_barrier(0);
    asm volatile("s_barrier" ::: "memory");
    if (kt + 2 < nt) STAGE(cur, kt + 2);
  }

  const float s0 = tabs4[0];
#pragma unroll
  for (int mi = 0; mi < 4; ++mi) {
#pragma unroll
    for (int ni = 0; ni < NFR; ++ni) {
      const int col0 = n0 + wc + ni * 16;   // frag-uniform (16-aligned)
      float scale = s0;
      if (QKVMODE) scale = col0 < 2048 ? s0 : (col0 < 2560 ? tabs4[1] : tabs4[2]);
      if (QKVMODE && col0 >= 2560) {
        const int vcol = col0 - 2560 + lo;
        const int row = m0 + wr + mi * 16 + hi * 4;
        unsigned w01 = cvt_pk_bf16(acc[mi][ni][0] * scale, acc[mi][ni][1] * scale);
        unsigned w23 = cvt_pk_bf16(acc[mi][ni][2] * scale, acc[mi][ni][3] * scale);
        uint2 pk; pk.x = w01; pk.y = w23;
        *reinterpret_cast<uint2*>(vt + (size_t)vcol * MROWS + row) = pk;
      } else {
#pragma unroll
        for (int r = 0; r < 4; ++r) {
          const int row = m0 + wr + mi * 16 + hi * 4 + r;
          const int col = col0 + lo;
          const float v = acc[mi][ni][r] * scale;
          if (OUT_BF16)
            reinterpret_cast<u16*>(Cv)[(size_t)row * N + col] = f2bf(v);
          else
            reinterpret_cast<float*>(Cv)[(size_t)row * N + col] = v;
        }
      }
    }
  }
}

// ---------------- flash attention v14 (KVBLK=128 staging, 64-t compute) --------
// K big tile: [128 t][64 d] rows of 8 chunks; swizzle ch ^= row&7.
__device__ __forceinline__ void stage_k128(u16* dst, const u16* base,
                                           int tid, int wave) {
#pragma unroll
  for (int it = 0; it < 4; ++it) {
    const int c = it * 256 + tid;
    const int row = c >> 3;                       // 0..127 (t)
    const int ch = (c & 7) ^ (row & 7);           // pre-swizzled source
    lds_load16(dst + (it * 256 + wave * 64) * 8,
               base + (size_t)row * LDQKV + ch * 8);
  }
}

// V^T big tile: [64 d][128 t] rows of 16 chunks; swizzle low-3 chunk bits.
__device__ __forceinline__ void stage_v128(u16* dst, const u16* base,
                                           int tid, int wave) {
#pragma unroll
  for (int it = 0; it < 4; ++it) {
    const int c = it * 256 + tid;
    const int row = c >> 4;                       // 0..63 (d)
    const int ch = (c & 8) | ((c & 7) ^ (row & 7));
    lds_load16(dst + (it * 256 + wave * 64) * 8,
               base + (size_t)row * MROWS + ch * 8);
  }
}

// One 64-t sub-tile: QK^T -> (opt prefetch) -> mask -> online-SM -> PV.
#define SUB_BODY(MASKED, SUB, DO_PRE)                                          \
  {                                                                            \
    const int t0 = bt * 128 + (SUB) * 64;                                      \
    f32x16 sacc[2] = {};                                                       \
    __builtin_amdgcn_s_setprio(1);                                             \
    _Pragma("unroll")                                                          \
    for (int w = 0; w < 4; ++w) {                                              \
      _Pragma("unroll")                                                        \
      for (int nf = 0; nf < 2; ++nf) {                                         \
        bf16x8 kf = *reinterpret_cast<const bf16x8*>(                          \
            &lKc[((SUB) * 64 + nf * 32 + q31) * 64 +                           \
                 ((w * 16 + hi5 * 8) ^ swl)]);                                 \
        sacc[nf] = __builtin_amdgcn_mfma_f32_32x32x16_bf16(                    \
            kf, qf[w], sacc[nf], 0, 0, 0);                                     \
      }                                                                        \
    }                                                                          \
    __builtin_amdgcn_s_setprio(0);                                             \
    if (DO_PRE) {                                                              \
      stage_k128(lK[cur ^ 1],                                                  \
                 Kb + (size_t)(brow + (bt + 1) * 128) * LDQKV, tid, wave);     \
      stage_v128(lV[cur ^ 1], Vb + (bt + 1) * 128, tid, wave);                 \
    }                                                                          \
    if (MASKED) {                                                              \
      _Pragma("unroll")                                                        \
      for (int nf = 0; nf < 2; ++nf) {                                         \
        _Pragma("unroll")                                                      \
        for (int rg = 0; rg < 16; ++rg) {                                      \
          const int tg = t0 + nf * 32 + (rg >> 2) * 8 + hi5 * 4 + (rg & 3);    \
          if (tg > qg) sacc[nf][rg] = -1e30f;                                  \
        }                                                                      \
      }                                                                        \
    }                                                                          \
    float mt = -1e30f;                                                         \
    _Pragma("unroll")                                                          \
    for (int nf = 0; nf < 2; ++nf) {                                           \
      _Pragma("unroll")                                                        \
      for (int rg = 0; rg < 16; ++rg) mt = fmaxf(mt, sacc[nf][rg]);            \
    }                                                                          \
    mt = fmaxf(mt, __shfl_xor(mt, 32));                                        \
    if (!__all((int)(mt <= m_run + THR_LOG2))) {                               \
      const float mn = fmaxf(m_run, mt);                                       \
      const float alpha = exp2_fast(m_run - mn);                               \
      m_run = mn;                                                              \
      l_lane *= alpha;                                                         \
      _Pragma("unroll")                                                        \
      for (int nf = 0; nf < 2; ++nf) {                                         \
        _Pragma("unroll")                                                      \
        for (int rg = 0; rg < 16; ++rg) oacc[nf][rg] *= alpha;                 \
      }                                                                        \
    }                                                                          \
    unsigned pk[2][8];                                                         \
    _Pragma("unroll")                                                          \
    for (int nf = 0; nf < 2; ++nf) {                                           \
      _Pragma("unroll")                                                        \
      for (int c = 0; c < 4; ++c) {                                            \
        const float e0 = exp2_fast(sacc[nf][4 * c + 0] - m_run);               \
        const float e1 = exp2_fast(sacc[nf][4 * c + 1] - m_run);               \
        const float e2 = exp2_fast(sacc[nf][4 * c + 2] - m_run);               \
        const float e3 = exp2_fast(sacc[nf][4 * c + 3] - m_run);               \
        l_lane += (e0 + e1) + (e2 + e3);                                       \
        pk[nf][2 * c + 0] = cvt_pk_bf16(e0, e1);                               \
        pk[nf][2 * c + 1] = cvt_pk_bf16(e2, e3);                               \
      }                                                                        \
    }                                                                          \
    __builtin_amdgcn_s_setprio(1);                                             \
    _Pragma("unroll")                                                          \
    for (int w = 0; w < 4; ++w) {                                              \
      const int nf_ = w >> 1, c4_ = (w & 1) * 4;                               \
      unsigned a0 = pk[nf_][c4_ + 0], a1 = pk[nf_][c4_ + 1];                   \
      unsigned b0 = pk[nf_][c4_ + 2], b1 = pk[nf_][c4_ + 3];                   \
      asm volatile("v_permlane32_swap_b32 %0, %1" : "+v"(a0), "+v"(b0));       \
      asm volatile("v_permlane32_swap_b32 %0, %1" : "+v"(a1), "+v"(b1));       \
      u32x4 pw; pw.x = a0; pw.y = a1; pw.z = b0; pw.w = b1;                    \
      bf16x8 pfr = *reinterpret_cast<const bf16x8*>(&pw);                      \
      _Pragma("unroll")                                                        \
      for (int nfo = 0; nfo < 2; ++nfo) {                                      \
        bf16x8 vf = *reinterpret_cast<const bf16x8*>(                          \
            &lVc[(nfo * 32 + q31) * 128 +                                      \
                 (((SUB) * 64 + w * 16 + hi5 * 8) ^ swl)]);                    \
        oacc[nfo] = __builtin_amdgcn_mfma_f32_32x32x16_bf16(                   \
            vf, pfr, oacc[nfo], 0, 0, 0);                                      \
      }                                                                        \
    }                                                                          \
    __builtin_amdgcn_s_setprio(0);                                             \
  }

__global__ __launch_bounds__(256, 2) void flash_attn(
    const u16* __restrict__ QKV, const u16* __restrict__ VT,
    u16* __restrict__ Og) {
  __shared__ u16 lK[2][128 * 64];   // [t][d], XOR-swizzled chunks (32 KB)
  __shared__ u16 lV[2][64 * 128];   // [d][t], XOR-swizzled chunks (32 KB)

  const int tid = threadIdx.x;
  const int lane = tid & 63, wave = tid >> 6;
  const int q31 = lane & 31, hi5 = lane >> 5;
  // XCD group pinning (round-8): each (b,kv) group's 32 blocks on one XCD.
  const int lin = (int)blockIdx.y * 8 + (int)blockIdx.x;   // 0..511
  const int xcd = lin & 7, slot = lin >> 3;
  const int G = xcd * 2 + (slot >> 5);    // 0..15 = (b, kv)
  const int wb = slot & 31;               // 0..31 = (g_h, lbx)
  const int b = G >> 3, kv = G & 7;
  const int h = kv * 4 + (wb >> 3);
  const int lbx = wb & 7;
  const int brow = b * S_LEN;
  const u16* Q  = QKV + h * HD;
  const u16* Kb = QKV + 2048 + kv * HD;                   // row stride LDQKV
  const u16* Vb = VT + (size_t)(kv * HD) * MROWS + brow;  // row d, stride MROWS
  const int swl = (lane & 7) << 3;

#pragma unroll 1
  for (int pi = 0; pi < 2; ++pi) {
    const int qt = pi == 0 ? lbx : (15 - lbx);
    const int q0 = qt * 128;
    const int q0w = q0 + wave * 32;
    const int nbt = qt + 1;            // big (128-t) tiles
    const int qg = q0w + q31;          // lane's q row
    int cur = 0;

    // Q fragments: lane holds Q[q][16w + 8*hi5 .. +8] per window w
    bf16x8 qf[4];
    {
      const size_t qr = (size_t)(brow + q0w + q31) * LDQKV;
#pragma unroll
      for (int w = 0; w < 4; ++w)
        qf[w] = *reinterpret_cast<const bf16x8*>(&Q[qr + w * 16 + hi5 * 8]);
    }

    f32x16 oacc[2] = {};
    float m_run = -1e30f, l_lane = 0.f;

    // prologue: stage big tile 0
    stage_k128(lK[0], Kb + (size_t)brow * LDQKV, tid, wave);
    stage_v128(lV[0], Vb, tid, wave);
    __syncthreads();

    // full big tiles (no masking; prefetch next at sub0)
#pragma unroll 1
    for (int bt = 0; bt < nbt - 1; ++bt) {
      u16* lKc = (u16*)lK[cur];
      u16* lVc = (u16*)lV[cur];
      SUB_BODY(0, 0, 1)
      SUB_BODY(0, 1, 0)
      __syncthreads();
      cur ^= 1;
    }
    // last (diagonal) big tile: masked subs, no prefetch
    {
      const int bt = nbt - 1;
      u16* lKc = (u16*)lK[cur];
      u16* lVc = (u16*)lV[cur];
      SUB_BODY(1, 0, 0)
      SUB_BODY(1, 1, 0)
      __syncthreads();
      cur ^= 1;
    }

    // ---- epilogue: l across lane pair, lane-local normalize, packed store ----
    {
      float ls = l_lane;
      ls += __shfl_xor(ls, 32);
      const float inv = 1.f / ls;
#pragma unroll
      for (int nfo = 0; nfo < 2; ++nfo) {
#pragma unroll
        for (int c = 0; c < 4; ++c) {
          const unsigned u0 = cvt_pk_bf16(oacc[nfo][4 * c + 0] * inv,
                                          oacc[nfo][4 * c + 1] * inv);
          const unsigned u1 = cvt_pk_bf16(oacc[nfo][4 * c + 2] * inv,
                                          oacc[nfo][4 * c + 3] * inv);
          const int d = nfo * 32 + c * 8 + hi5 * 4;
          uint2 st; st.x = u0; st.y = u1;
          *reinterpret_cast<uint2*>(
              &Og[(size_t)(brow + q0w + q31) * D_MODEL + h * HD + d]) = st;
        }
      }
    }
  }
}

// ---------------- launcher ----------------
extern "C" void kernel_launch(void* const* d_in, const int* in_sizes, int n_in,
                              void* d_out, int out_size, void* d_ws, size_t ws_size,
                              hipStream_t stream) {
  (void)in_sizes; (void)n_in; (void)out_size; (void)ws_size;
  const float* x  = (const float*)d_in[0];
  const float* wq = (const float*)d_in[1];
  const float* wk = (const float*)d_in[2];
  const float* wv = (const float*)d_in[3];
  const float* wo = (const float*)d_in[4];
  float* out = (float*)d_out;
  char* ws = (char*)d_ws;

  double* partials = (double*)ws;            // 640 * 8 B
  float* tabs = (float*)(ws + 6144);         // 4 floats
  size_t off = 8192;
  u16* xb    = (u16*)(ws + off); off += (size_t)MROWS * D_MODEL * 2;
  u16* wqkvs = (u16*)(ws + off); off += (size_t)NQKV * D_MODEL * 2;
  u16* wos   = (u16*)(ws + off); off += (size_t)D_MODEL * D_MODEL * 2;
  u16* qkvb  = (u16*)(ws + off); off += (size_t)MROWS * NQKV * 2;
  u16* ao    = (u16*)(ws + off); off += (size_t)MROWS * D_MODEL * 2;
  u16* vt    = (u16*)(ws + off); off += (size_t)512 * MROWS * 2;

  // 1. fused prep: weight signs + |w| partials + x->bf16
  prep_all<<<1152, 256, 0, stream>>>(wq, wk, wv, wo, x, wqkvs, wos, xb, partials);
  finalize_scales<<<1, 256, 0, stream>>>(partials, tabs);

  // 2. fused QKV projection (BN=192 -> 512 blocks, exactly 2/CU)
  gemm_dp<192, 1, 1><<<dim3(NQKV / 192, MROWS / 128), 512, 0, stream>>>(
      xb, wqkvs, qkvb, tabs, vt, MROWS, NQKV, D_MODEL);

  // 3. GQA causal flash attention (paired, KVBLK=128 staging)
  flash_attn<<<dim3(8, 64), 256, 0, stream>>>(qkvb, vt, ao);

  // 4. output projection (BN=128 -> 512 blocks, f32 out)
  gemm_dp<128, 0, 0><<<dim3(D_MODEL / 128, MROWS / 128), 512, 0, stream>>>(
      ao, wos, out, tabs + 3, nullptr, MROWS, D_MODEL, D_MODEL);
}